// Round 7
// baseline (763.253 us; speedup 1.0000x reference)
//
#include <hip/hip_runtime.h>

#define EPS 1e-6f
#define NSTEPS 4
#define TPB 64            // 1-wave blocks: barriers lower to wave-level sync
#define GROUPS 2          // 32-lane solve groups per block
#define TPG 2             // batch tiles solved simultaneously per group
#define TILES (GROUPS * TPG)   // 4 tiles resident in LDS per block

// XOR-swizzled tile addressing: tile is 32x32 floats, 4096 B, NO padding.
// addr(row,col) = row*32 + (col ^ row).
//  - row access (fixed col-iter i, lanes r): banks i^r  -> all distinct
//  - col access (fixed row-iter i, lanes r): banks r^i  -> all distinct
//  - float4 staging (row=4j+(r>>3), col=4(r&7)+k): banks ((b^j)<<2)|(k^a),
//    all 32 distinct
// => conflict-free everywhere with 4096 B/tile instead of 4224 (PITCH 33).
// 4 tiles/block = 16384 B  ->  163840/16384 = 10 blocks/CU = 10 waves/CU
// (vs R4's 8). This is the occupancy lever; register structure is R4's.
__device__ __forceinline__ int swz(int row, int col) {
    return (row << 5) | (col ^ row);
}

// ---------------------------------------------------------------------------
// Kernel 1: precompute Thomas coefficients per (step, c, solve-line).
// P[((s*3+c)*32 + i)*32 + lane] = float4(a_i, 1/denom_i, cs_i, 0)
// lane = h (x-dir) or w (y-dir); i = position along the solve direction.
// (Identical to the proven R1/R4 version.)
// ---------------------------------------------------------------------------
__global__ void coeff_kernel(const float* __restrict__ ab,
                             const float* __restrict__ atc,
                             const float* __restrict__ bb,
                             const float* __restrict__ btc,
                             float4* __restrict__ PX,
                             float4* __restrict__ PY)
{
    int tid = blockIdx.x * blockDim.x + threadIdx.x;
    if (tid >= 768) return;                 // 2 dirs * 4 steps * 3 ch * 32 lanes
    int lane = tid & 31;
    int rest = tid >> 5;                    // 0..23
    int c    = rest % 3;
    int s    = (rest / 3) & 3;
    int dir  = rest / 12;                   // 0 = x, 1 = y
    float t  = 0.15f * (float)s;

    float A[32];
    float dt;
    if (dir == 0) {
        int h = lane;
        const float* pa = ab  + (c * 32 + h) * 32;
        const float* pt = atc + (c * 32 + h) * 32;
        #pragma unroll
        for (int w = 0; w < 32; w++)
            A[w] = fmaxf(pa[w] + t * pt[w], EPS);
        dt = 0.075f;                        // DT/2
    } else {
        int w = lane;
        #pragma unroll
        for (int h = 0; h < 32; h++)
            A[h] = fmaxf(bb[(c * 32 + h) * 32 + w] + t * btc[(c * 32 + h) * 32 + w], EPS);
        dt = 0.15f;                         // DT
    }

    // 3-tap mean with replicate padding
    float S[32];
    #pragma unroll
    for (int i = 0; i < 32; i++) {
        float l = A[(i == 0) ? 0 : i - 1];
        float r = A[(i == 31) ? 31 : i + 1];
        S[i] = (l + A[i] + r) / 3.0f;
    }

    float4* dst = (dir == 0 ? PX : PY) + ((s * 3 + c) * 32) * 32 + lane;
    float cp = 0.0f;
    for (int i = 0; i < 32; i++) {
        float co = S[i] * dt;               // coeff = smoothed * dt / DX^2 (DX=1)
        float a  = -co;
        float b  = (i == 0 || i == 31) ? (1.0f + co) : (1.0f + 2.0f * co);
        float cc = -co;
        float denom = (b - a * cp) + EPS;   // matches ref: eps added every step
        float inv = 1.0f / denom;           // precise division here (cheap)
        float cs  = cc / denom;
        if (i == 31) cs = 0.0f;             // ref zeroes c_star[N-1]
        dst[i * 32] = make_float4(a, inv, cs, 0.0f);
        cp = cs;
    }
}

// ---------------------------------------------------------------------------
// Kernel 2: fused 4-step ADI, EXACT R4 register structure (in-chain float4
// coefficient loads, csr in regs, 2 tiles per 32-lane group). R7 changes:
//  - XOR-swizzled unpadded LDS tiles (4096 B/tile, conflict-free both axes)
//  - TPB=64 single-wave blocks, TILES=4 -> LDS 16384/block -> 10 waves/CU
//    (R4: 33792 -> 4 blocks -> 8 waves/CU). Barriers become wave-local.
// __launch_bounds__(64,2): same allocator tier that gave R4 VGPR=124.
// Gate: VGPR <= 128 and WRITE_SIZE == 196608 KB (else allocator mis-tiered).
// ---------------------------------------------------------------------------
__global__ __launch_bounds__(TPB, 2)
void diffuse_kernel(const float* __restrict__ u,
                    const float4* __restrict__ PX,
                    const float4* __restrict__ PY,
                    const float* __restrict__ coupling,
                    float* __restrict__ out)
{
    __shared__ float lds[TILES * 1024];

    const int tid = threadIdx.x;
    const int g   = tid >> 5;               // group within block (0..1)
    const int r   = tid & 31;               // lane within group
    // consecutive blocks share c: co-resident blocks keep the same 32 KB
    // coefficient slab hot in L1
    const int nper = gridDim.x / 3;         // blocks per channel (4096)
    const int c    = blockIdx.x / nper;
    const long grp = blockIdx.x % nper;
    const long bA  = grp * TILES + g * TPG; // batch of tile A
    const long baseA = (bA * 3 + c) << 10;  // 32*32 floats per (b,c) image
    const long baseB = baseA + 3072;        // batch bA+1, same c: +3*1024 floats

    float* TA = lds + (g * TPG + 0) * 1024;
    float* TB = lds + (g * TPG + 1) * 1024;

    // ---- stage global -> LDS (coalesced float4 loads, swizzled scatter) ----
    const float4* sA = (const float4*)(u + baseA);
    const float4* sB = (const float4*)(u + baseB);
    #pragma unroll
    for (int j = 0; j < 8; j++) {
        float4 va = sA[j * 32 + r];
        float4 vb = sB[j * 32 + r];
        int f = (j * 32 + r) * 4;           // linear float index in tile
        int row = f >> 5, col = f & 31;     // col is a multiple of 4
        TA[swz(row, col + 0)] = va.x; TA[swz(row, col + 1)] = va.y;
        TA[swz(row, col + 2)] = va.z; TA[swz(row, col + 3)] = va.w;
        TB[swz(row, col + 0)] = vb.x; TB[swz(row, col + 1)] = vb.y;
        TB[swz(row, col + 2)] = vb.z; TB[swz(row, col + 3)] = vb.w;
    }
    const float kc = coupling[c * 3 + c];
    __syncthreads();

    float valA[32], valB[32];
    float csr[32];

    #pragma unroll 1
    for (int s = 0; s < NSTEPS; s++) {
        const float4* px = PX + (s * 3 + c) * 1024 + r;
        const float4* py = PY + (s * 3 + c) * 1024 + r;

        // ---------- x half-step #1 (thread = row r) ----------
        {
            float dpA = 0.0f, dpB = 0.0f;
            #pragma unroll
            for (int i = 0; i < 32; i++) {
                float4 p  = px[i * 32];
                float dA  = (s == 0) ? TA[swz(r, i)] : valA[i];
                float dB  = (s == 0) ? TB[swz(r, i)] : valB[i];
                dpA = (dA - p.x * dpA) * p.y;
                dpB = (dB - p.x * dpB) * p.y;
                valA[i] = dpA;
                valB[i] = dpB;
                csr[i]  = p.z;
            }
            float xA = 0.0f, xB = 0.0f;
            #pragma unroll
            for (int i = 31; i >= 0; i--) {
                xA = valA[i] - csr[i] * xA;
                xB = valB[i] - csr[i] * xB;
                TA[swz(r, i)] = xA;         // expose rows for y transpose
                TB[swz(r, i)] = xB;
            }
        }
        __syncthreads();

        // ---------- y full step (thread = col r) ----------
        {
            float dpA = 0.0f, dpB = 0.0f;
            #pragma unroll
            for (int i = 0; i < 32; i++) {
                float4 p  = py[i * 32];
                float dA  = TA[swz(i, r)];
                float dB  = TB[swz(i, r)];
                dpA = (dA - p.x * dpA) * p.y;
                dpB = (dB - p.x * dpB) * p.y;
                valA[i] = dpA;
                valB[i] = dpB;
                csr[i]  = p.z;
            }
            float xA = 0.0f, xB = 0.0f;
            #pragma unroll
            for (int i = 31; i >= 0; i--) {
                xA = valA[i] - csr[i] * xA;
                xB = valB[i] - csr[i] * xB;
                TA[swz(i, r)] = xA;         // expose cols for x transpose
                TB[swz(i, r)] = xB;
            }
        }
        __syncthreads();

        // ---------- x half-step #2 (thread = row r), result + scale in regs ----------
        {
            float dpA = 0.0f, dpB = 0.0f;
            #pragma unroll
            for (int i = 0; i < 32; i++) {
                float4 p  = px[i * 32];
                float dA  = TA[swz(r, i)];
                float dB  = TB[swz(r, i)];
                dpA = (dA - p.x * dpA) * p.y;
                dpB = (dB - p.x * dpB) * p.y;
                valA[i] = dpA;
                valB[i] = dpB;
                csr[i]  = p.z;
            }
            float xA = 0.0f, xB = 0.0f;
            #pragma unroll
            for (int i = 31; i >= 0; i--) {
                xA = valA[i] - csr[i] * xA;  // backward uses UNSCALED neighbor
                xB = valB[i] - csr[i] * xB;
                valA[i] = kc * xA;           // channel-diagonal scale
                valB[i] = kc * xB;
            }
        }
        // no barrier needed: x2 and next x1 touch only this thread's rows
    }

    // ---- write back: regs -> LDS rows -> coalesced global float4 ----
    #pragma unroll
    for (int i = 0; i < 32; i++) {
        TA[swz(r, i)] = valA[i];
        TB[swz(r, i)] = valB[i];
    }
    __syncthreads();

    float4* dA4 = (float4*)(out + baseA);
    float4* dB4 = (float4*)(out + baseB);
    #pragma unroll
    for (int j = 0; j < 8; j++) {
        int f = (j * 32 + r) * 4;
        int row = f >> 5, col = f & 31;
        dA4[j * 32 + r] = make_float4(TA[swz(row, col + 0)], TA[swz(row, col + 1)],
                                      TA[swz(row, col + 2)], TA[swz(row, col + 3)]);
        dB4[j * 32 + r] = make_float4(TB[swz(row, col + 0)], TB[swz(row, col + 1)],
                                      TB[swz(row, col + 2)], TB[swz(row, col + 3)]);
    }
}

// ---------------------------------------------------------------------------
extern "C" void kernel_launch(void* const* d_in, const int* in_sizes, int n_in,
                              void* d_out, int out_size, void* d_ws, size_t ws_size,
                              hipStream_t stream) {
    const float* u   = (const float*)d_in[0];
    const float* ab  = (const float*)d_in[1];  // alpha_base
    const float* bb  = (const float*)d_in[2];  // beta_base
    const float* atc = (const float*)d_in[3];  // alpha_time_coeff
    const float* btc = (const float*)d_in[4];  // beta_time_coeff
    const float* cpl = (const float*)d_in[5];  // channel_coupling [3][3]
    float* out = (float*)d_out;

    // workspace: PX (192 KB) then PY (192 KB)
    float4* PX = (float4*)d_ws;
    float4* PY = PX + 4 * 3 * 32 * 32;

    coeff_kernel<<<3, 256, 0, stream>>>(ab, atc, bb, btc, PX, PY);

    int B = in_sizes[0] / (3 * 32 * 32);       // 16384
    int nblocks = (B / TILES) * 3;             // 12288 one-wave blocks
    diffuse_kernel<<<nblocks, TPB, 0, stream>>>(u, PX, PY, cpl, out);
}